// Round 3
// baseline (212.084 us; speedup 1.0000x reference)
//
#include <hip/hip_runtime.h>
#include <hip/hip_bf16.h>
#include <math.h>

typedef __bf16 bf16x8 __attribute__((ext_vector_type(8)));
typedef float f32x4 __attribute__((ext_vector_type(4)));

#define GAS __attribute__((address_space(1)))
#define LAS __attribute__((address_space(3)))

static __device__ __forceinline__ void load16(const void* g, void* l) {
    __builtin_amdgcn_global_load_lds((const GAS void*)g, (LAS void*)l, 16, 0, 0);
}

struct __align__(8) bh4 { __hip_bfloat16 x, y, z, w; };

// ---------- fused LayerNorm (blocks 0..nln-1) + weight cast (blocks nln..) ----------
__global__ __launch_bounds__(256) void pre_kernel(
        const float* __restrict__ x, const float* __restrict__ gamma,
        const float* __restrict__ beta, const float* __restrict__ w1,
        const float* __restrict__ w2, __hip_bfloat16* __restrict__ hn,
        __hip_bfloat16* __restrict__ w1b, __hip_bfloat16* __restrict__ w2b, int nln) {
    if ((int)blockIdx.x >= nln) {   // weight cast: 1024 blocks x 256 thr x 4 elems
        const int i = (blockIdx.x - nln) * 256 + threadIdx.x;
        float4 a = ((const float4*)w1)[i];
        float4 b = ((const float4*)w2)[i];
        bh4 r1, r2;
        r1.x = __float2bfloat16(a.x); r1.y = __float2bfloat16(a.y);
        r1.z = __float2bfloat16(a.z); r1.w = __float2bfloat16(a.w);
        r2.x = __float2bfloat16(b.x); r2.y = __float2bfloat16(b.y);
        r2.z = __float2bfloat16(b.z); r2.w = __float2bfloat16(b.w);
        ((bh4*)w1b)[i] = r1;
        ((bh4*)w2b)[i] = r2;
        return;
    }
    const int row  = (blockIdx.x << 2) + (threadIdx.x >> 6);
    const int lane = threadIdx.x & 63;
    const float4* px = (const float4*)(x + (size_t)row * 1024);
    float4 v[4];
    float s = 0.f;
#pragma unroll
    for (int i = 0; i < 4; ++i) {
        v[i] = px[lane + (i << 6)];
        s += v[i].x + v[i].y + v[i].z + v[i].w;
    }
#pragma unroll
    for (int o = 32; o; o >>= 1) s += __shfl_xor(s, o, 64);
    const float mu = s * (1.0f / 1024.0f);
    float vs = 0.f;
#pragma unroll
    for (int i = 0; i < 4; ++i) {
        float a = v[i].x - mu, b = v[i].y - mu, c = v[i].z - mu, d = v[i].w - mu;
        vs += a * a + b * b + c * c + d * d;
    }
#pragma unroll
    for (int o = 32; o; o >>= 1) vs += __shfl_xor(vs, o, 64);
    const float rs = rsqrtf(vs * (1.0f / 1024.0f) + 1e-5f);
    const float4* pg = (const float4*)gamma;
    const float4* pb = (const float4*)beta;
    bh4* po = (bh4*)(hn + (size_t)row * 1024);
#pragma unroll
    for (int i = 0; i < 4; ++i) {
        const int idx = lane + (i << 6);
        float4 g = pg[idx], bb = pb[idx];
        bh4 r;
        r.x = __float2bfloat16((v[i].x - mu) * rs * g.x + bb.x);
        r.y = __float2bfloat16((v[i].y - mu) * rs * g.y + bb.y);
        r.z = __float2bfloat16((v[i].z - mu) * rs * g.z + bb.z);
        r.w = __float2bfloat16((v[i].w - mu) * rs * g.w + bb.w);
        po[idx] = r;
    }
}

// fast exact-GELU: erf via Abramowitz-Stegun 7.1.26 (|eps| <= 1.5e-7, branchless).
__device__ __forceinline__ float gelu_exact(float v) {
    const float ax = fabsf(v) * 0.70710678118654752f;
    const float t  = __builtin_amdgcn_rcpf(__builtin_fmaf(0.3275911f, ax, 1.0f));
    float p = __builtin_fmaf(1.061405429f, t, -1.453152027f);
    p = __builtin_fmaf(p, t, 1.421413741f);
    p = __builtin_fmaf(p, t, -0.284496736f);
    p = __builtin_fmaf(p, t, 0.254829592f);
    p *= t;
    const float e  = __expf(-ax * ax);
    const float er = __builtin_fmaf(-p, e, 1.0f);     // erf(|x|) in [0,1)
    return 0.5f * v * (1.0f + copysignf(er, v));
}

// ================= 256x256 GEMM (B^T weights), BK=64, mfma 16x16x32 ===============
// 8 waves (2 row x 4 col), per-wave C = 128x64. LDS 128 KiB: A dbuf 2x32KB, B dbuf
// 2x32KB; rows of 128 B (8 chunks of 16 B), XOR chunk swizzle:
//   sA physical chunk p = logical ^ (row&7); sB p = logical ^ ((row>>2)&7).
// global_load_lds dst linear (base + tid*16); source chunk pre-permuted.
//
// Lockstep 4-phase tile (2 bars/phase, m201 rhythm) + DEEP uniform staging, 2 loads
// per phase, never draining vmcnt in the main loop. Stage ledger (tile t):
//  P1: ds aF-mh0(8)+bF0(4) | stage A(t+1)h1->OTH  (legal: t-1's A readers done)
//      | lgkm(8) | bar | lgkm0 | MFMA(0,0) | bar
//  P2: ds bF1(4)           | stage B(t+1)h1->OTH  | bar | lgkm0 | MFMA(0,1) | bar
//  P3: ds aF-mh1(8)        | stage B(t+2)h0->CUR  (legal: all B(t) reads done by
//      P2's bar; B rows [wc*64..wc*64+63] read only in P1/P2) | bar | lgkm0
//      | MFMA(1,1) | bar
//  P4:                     | stage A(t+2)h0->CUR  (legal: A h0 rows read only by
//      wr=0 waves, retired by their P3 lgkm0, all-waves at P3's bar) | bar
//      | MFMA(1,0) | vmcnt(4) | bar
// Steady state: 12 loads in flight; tile-end vmcnt(4) retires exactly
// [A(t+1),B(t+1)] (4-7-phase windows, covers HBM rate) leaving
// [B(t+2)h0, A(t+2)h0] flying.
#define SCB() __builtin_amdgcn_sched_barrier(0)
#define BAR() do { __builtin_amdgcn_s_barrier(); SCB(); } while (0)
#define LGKM0() do { asm volatile("s_waitcnt lgkmcnt(0)" ::: "memory"); SCB(); } while (0)
#define LGKMH() do { asm volatile("s_waitcnt lgkmcnt(8)" ::: "memory"); SCB(); } while (0)
#define VMW(n) do { asm volatile("s_waitcnt vmcnt(" #n ")" ::: "memory"); SCB(); } while (0)

__device__ __forceinline__ void rdA(const char* base, bf16x8 (&aF)[4][2], int px0, int px1) {
#pragma unroll
    for (int ii = 0; ii < 4; ++ii) {
        aF[ii][0] = *(const bf16x8*)(base + ii * 2048 + px0);
        aF[ii][1] = *(const bf16x8*)(base + ii * 2048 + px1);
    }
}
__device__ __forceinline__ void rdB(const char* base, bf16x8 (&bF)[2][2], int px0, int px1) {
#pragma unroll
    for (int jj = 0; jj < 2; ++jj) {
        bF[jj][0] = *(const bf16x8*)(base + jj * 128 + px0);
        bF[jj][1] = *(const bf16x8*)(base + jj * 128 + px1);
    }
}
template <int MI, int NI>
__device__ __forceinline__ void mfmaQ(f32x4 (&acc)[8][4], const bf16x8 (&aF)[4][2],
                                      const bf16x8 (&bF)[2][2]) {
    __builtin_amdgcn_s_setprio(1);
#pragma unroll
    for (int ii = 0; ii < 4; ++ii)
#pragma unroll
        for (int jj = 0; jj < 2; ++jj) {
            acc[MI * 4 + ii][NI * 2 + jj] = __builtin_amdgcn_mfma_f32_16x16x32_bf16(
                aF[ii][0], bF[jj][0], acc[MI * 4 + ii][NI * 2 + jj], 0, 0, 0);
            acc[MI * 4 + ii][NI * 2 + jj] = __builtin_amdgcn_mfma_f32_16x16x32_bf16(
                aF[ii][1], bF[jj][1], acc[MI * 4 + ii][NI * 2 + jj], 0, 0, 0);
        }
    __builtin_amdgcn_s_setprio(0);
}

// KOFF in elements (= t*64). 131072 elems = 128 rows * K. S1 gates (t+1) stages
// (P1/P2), S2 gates (t+2) stages (P3/P4).
#define TILE(CUR, OTH, KOFF, S1, S2) do { \
    const char* aB_ = aRd + (CUR) * 32768; \
    const char* bB_ = bRd + (CUR) * 32768; \
    /* P1 */ \
    rdA(aB_, aF, px0, px1); \
    rdB(bB_, bF0, px0, px1); \
    if (S1) { load16(aS0 + 131072 + (KOFF) + 64, dA + (OTH) * 32768 + 16384); \
              load16(aS1 + 131072 + (KOFF) + 64, dA + (OTH) * 32768 + 24576); } \
    LGKMH(); \
    BAR(); LGKM0(); mfmaQ<0, 0>(acc, aF, bF0); BAR(); \
    /* P2 */ \
    rdB(bB_ + 256, bF1, px0, px1); \
    if (S1) { load16(bS0 + 131072 + (KOFF) + 64, dB + (OTH) * 32768 + 16384); \
              load16(bS1 + 131072 + (KOFF) + 64, dB + (OTH) * 32768 + 24576); } \
    BAR(); LGKM0(); mfmaQ<0, 1>(acc, aF, bF1); BAR(); \
    /* P3 */ \
    rdA(aB_ + 8192, aF, px0, px1); \
    if (S2) { load16(bS0 + (KOFF) + 128, dB + (CUR) * 32768); \
              load16(bS1 + (KOFF) + 128, dB + (CUR) * 32768 + 8192); } \
    BAR(); LGKM0(); mfmaQ<1, 1>(acc, aF, bF1); BAR(); \
    /* P4 */ \
    if (S2) { load16(aS0 + (KOFF) + 128, dA + (CUR) * 32768); \
              load16(aS1 + (KOFF) + 128, dA + (CUR) * 32768 + 8192); } \
    BAR(); mfmaQ<1, 0>(acc, aF, bF0); \
} while (0)

template <int EPI>
__global__ __launch_bounds__(512, 2) void gemm256(
        const __hip_bfloat16* __restrict__ A,
        const __hip_bfloat16* __restrict__ B,
        const float* __restrict__ bias,
        const float* __restrict__ resid,
        __hip_bfloat16* __restrict__ outb,
        float* __restrict__ outf) {
    constexpr int K = 1024, N = 1024;
    __shared__ __align__(16) char lds[131072];
    char* sA = lds;            // 2 x 32KB A buffers
    char* sB = lds + 65536;    // 2 x 32KB B buffers

    const int tid  = threadIdx.x;
    const int lane = tid & 63;
    const int w    = tid >> 6;
    const int wr   = w >> 2;       // 0..1 wave row
    const int wc   = w & 3;        // 0..3 wave col
    const int f    = lane & 15;
    const int h    = lane >> 4;
    const int bm   = blockIdx.x * 256;
    const int bn   = blockIdx.y * 256;

    // staging sources: half of 128 rows x 8 chunks = 1024 chunk-ids; 512 thr x 2 loads
    const int cid0 = tid, cid1 = tid + 512;
    const __hip_bfloat16* aS0 = A + (size_t)(bm + (cid0 >> 3)) * K + (((cid0 & 7) ^ ((cid0 >> 3) & 7)) << 3);
    const __hip_bfloat16* aS1 = A + (size_t)(bm + (cid1 >> 3)) * K + (((cid1 & 7) ^ ((cid1 >> 3) & 7)) << 3);
    const __hip_bfloat16* bS0 = B + (size_t)(bn + (cid0 >> 3)) * K + (((cid0 & 7) ^ ((cid0 >> 5) & 7)) << 3);
    const __hip_bfloat16* bS1 = B + (size_t)(bn + (cid1 >> 3)) * K + (((cid1 & 7) ^ ((cid1 >> 5) & 7)) << 3);
    char* dA = sA + tid * 16;  // linear dst; per-wave uniform base + lane*16
    char* dB = sB + tid * 16;

    // fragment read bases (verified layout)
    const int pxk = (f & 7) * 16;
    const int px0 = (h * 16) ^ pxk;
    const int px1 = ((4 + h) * 16) ^ pxk;
    const char* aRd = sA + (size_t)(wr * 128 + f) * 128;    // + buf + mh*8192 + ii*2048 + px
    const char* bRd = sB + (size_t)(wc * 64 + 4 * f) * 128; // + buf + j*128 + px

    f32x4 acc[8][4] = {};
    bf16x8 aF[4][2], bF0[2][2], bF1[2][2];

    // prologue (issue order defines vmcnt ledger):
    // B(0)h0, B(0)h1, A(0)h0, A(0)h1 -> buf0; B(1)h0, A(1)h0 -> buf1.
    // vmcnt(4): waits B(0),A(0); leaves [B(1)h0, A(1)h0] = steady-state leftover.
    load16(bS0, dB);                  load16(bS1, dB + 8192);
    load16(bS0 + 131072, dB + 16384); load16(bS1 + 131072, dB + 24576);
    load16(aS0, dA);                  load16(aS1, dA + 8192);
    load16(aS0 + 131072, dA + 16384); load16(aS1 + 131072, dA + 24576);
    load16(bS0 + 64, dB + 32768);     load16(bS1 + 64, dB + 32768 + 8192);
    load16(aS0 + 64, dA + 32768);     load16(aS1 + 64, dA + 32768 + 8192);
    VMW(4);
    BAR();

#pragma unroll 1
    for (int it = 0; it < 7; ++it) {          // t = 0..13
        const int k0 = it << 7;
        TILE(0, 1, k0, true, true);
        VMW(4); BAR();
        TILE(1, 0, k0 + 64, true, true);
        VMW(4); BAR();
    }
    // t = 14: stage tile-15 halves (P1/P2), no t+2 stages; drain all before t=15
    TILE(0, 1, 896, true, false);
    VMW(0); BAR();
    // t = 15: no stages, no end wait
    TILE(1, 0, 960, false, false);

    // epilogue: lane owns rows bm+wr*128+i*16+h*4+r, cols bn+wc*64+4f..+3 (j contiguous)
    const int colb = bn + wc * 64 + f * 4;
    const float4 bias4 = *(const float4*)(bias + colb);
#pragma unroll
    for (int i = 0; i < 8; ++i) {
#pragma unroll
        for (int r = 0; r < 4; ++r) {
            const size_t grow = (size_t)(bm + wr * 128 + i * 16 + h * 4 + r);
            float v0 = acc[i][0][r] + bias4.x;
            float v1 = acc[i][1][r] + bias4.y;
            float v2 = acc[i][2][r] + bias4.z;
            float v3 = acc[i][3][r] + bias4.w;
            if (EPI == 0) {
                bh4 o;
                o.x = __float2bfloat16(gelu_exact(v0));
                o.y = __float2bfloat16(gelu_exact(v1));
                o.z = __float2bfloat16(gelu_exact(v2));
                o.w = __float2bfloat16(gelu_exact(v3));
                *(bh4*)(outb + grow * N + colb) = o;
            } else {
                const float4 rs = *(const float4*)(resid + grow * N + colb);
                float4 o = {v0 + rs.x, v1 + rs.y, v2 + rs.z, v3 + rs.w};
                *(float4*)(outf + grow * N + colb) = o;
            }
        }
    }
}

extern "C" void kernel_launch(void* const* d_in, const int* in_sizes, int n_in,
                              void* d_out, int out_size, void* d_ws, size_t ws_size,
                              hipStream_t stream) {
    const float* x     = (const float*)d_in[0];
    const float* gamma = (const float*)d_in[1];
    const float* beta  = (const float*)d_in[2];
    const float* w1    = (const float*)d_in[3];
    const float* b1    = (const float*)d_in[4];
    const float* w2    = (const float*)d_in[5];
    const float* b2    = (const float*)d_in[6];
    float* out = (float*)d_out;

    const int M = in_sizes[0] / 1024;   // 16384

    char* ws = (char*)d_ws;
    __hip_bfloat16* hn  = (__hip_bfloat16*)ws;                          // 32 MiB
    __hip_bfloat16* h1  = (__hip_bfloat16*)(ws + (size_t)M * 2048);     // 32 MiB
    __hip_bfloat16* w1b = (__hip_bfloat16*)(ws + (size_t)M * 4096);     // 2 MiB
    __hip_bfloat16* w2b = (__hip_bfloat16*)(ws + (size_t)M * 4096 + 2097152);

    const int nln = M / 4;   // 4096 LN blocks + 1024 cvt blocks
    pre_kernel<<<nln + 1024, 256, 0, stream>>>(x, gamma, beta, w1, w2, hn, w1b, w2b, nln);
    // grid x = bm index: linear id % 8 = bm % 8 -> the 4 bn-blocks of one bm strip
    // land on one XCD (A-strip L2 reuse); 256 blocks = exactly 1/CU.
    gemm256<0><<<dim3(M / 256, 4), 512, 0, stream>>>(hn, w1b, b1, nullptr, h1, nullptr);
    gemm256<1><<<dim3(M / 256, 4), 512, 0, stream>>>(h1, w2b, b2, x, nullptr, out);
}

// Round 4
// 206.011 us; speedup vs baseline: 1.0295x; 1.0295x over previous
//
#include <hip/hip_runtime.h>
#include <hip/hip_bf16.h>
#include <math.h>

typedef __bf16 bf16x8 __attribute__((ext_vector_type(8)));
typedef float f32x4 __attribute__((ext_vector_type(4)));

#define GAS __attribute__((address_space(1)))
#define LAS __attribute__((address_space(3)))

static __device__ __forceinline__ void load16(const void* g, void* l) {
    __builtin_amdgcn_global_load_lds((const GAS void*)g, (LAS void*)l, 16, 0, 0);
}

struct __align__(8) bh4 { __hip_bfloat16 x, y, z, w; };

// ---------- fused LayerNorm (blocks 0..nln-1) + weight cast (blocks nln..) ----------
__global__ __launch_bounds__(256) void pre_kernel(
        const float* __restrict__ x, const float* __restrict__ gamma,
        const float* __restrict__ beta, const float* __restrict__ w1,
        const float* __restrict__ w2, __hip_bfloat16* __restrict__ hn,
        __hip_bfloat16* __restrict__ w1b, __hip_bfloat16* __restrict__ w2b, int nln) {
    if ((int)blockIdx.x >= nln) {   // weight cast: 1024 blocks x 256 thr x 4 elems
        const int i = (blockIdx.x - nln) * 256 + threadIdx.x;
        float4 a = ((const float4*)w1)[i];
        float4 b = ((const float4*)w2)[i];
        bh4 r1, r2;
        r1.x = __float2bfloat16(a.x); r1.y = __float2bfloat16(a.y);
        r1.z = __float2bfloat16(a.z); r1.w = __float2bfloat16(a.w);
        r2.x = __float2bfloat16(b.x); r2.y = __float2bfloat16(b.y);
        r2.z = __float2bfloat16(b.z); r2.w = __float2bfloat16(b.w);
        ((bh4*)w1b)[i] = r1;
        ((bh4*)w2b)[i] = r2;
        return;
    }
    const int row  = (blockIdx.x << 2) + (threadIdx.x >> 6);
    const int lane = threadIdx.x & 63;
    const float4* px = (const float4*)(x + (size_t)row * 1024);
    float4 v[4];
    float s = 0.f;
#pragma unroll
    for (int i = 0; i < 4; ++i) {
        v[i] = px[lane + (i << 6)];
        s += v[i].x + v[i].y + v[i].z + v[i].w;
    }
#pragma unroll
    for (int o = 32; o; o >>= 1) s += __shfl_xor(s, o, 64);
    const float mu = s * (1.0f / 1024.0f);
    float vs = 0.f;
#pragma unroll
    for (int i = 0; i < 4; ++i) {
        float a = v[i].x - mu, b = v[i].y - mu, c = v[i].z - mu, d = v[i].w - mu;
        vs += a * a + b * b + c * c + d * d;
    }
#pragma unroll
    for (int o = 32; o; o >>= 1) vs += __shfl_xor(vs, o, 64);
    const float rs = rsqrtf(vs * (1.0f / 1024.0f) + 1e-5f);
    const float4* pg = (const float4*)gamma;
    const float4* pb = (const float4*)beta;
    bh4* po = (bh4*)(hn + (size_t)row * 1024);
#pragma unroll
    for (int i = 0; i < 4; ++i) {
        const int idx = lane + (i << 6);
        float4 g = pg[idx], bb = pb[idx];
        bh4 r;
        r.x = __float2bfloat16((v[i].x - mu) * rs * g.x + bb.x);
        r.y = __float2bfloat16((v[i].y - mu) * rs * g.y + bb.y);
        r.z = __float2bfloat16((v[i].z - mu) * rs * g.z + bb.z);
        r.w = __float2bfloat16((v[i].w - mu) * rs * g.w + bb.w);
        po[idx] = r;
    }
}

// fast exact-GELU: erf via Abramowitz-Stegun 7.1.26 (|eps| <= 1.5e-7, branchless).
__device__ __forceinline__ float gelu_exact(float v) {
    const float ax = fabsf(v) * 0.70710678118654752f;
    const float t  = __builtin_amdgcn_rcpf(__builtin_fmaf(0.3275911f, ax, 1.0f));
    float p = __builtin_fmaf(1.061405429f, t, -1.453152027f);
    p = __builtin_fmaf(p, t, 1.421413741f);
    p = __builtin_fmaf(p, t, -0.284496736f);
    p = __builtin_fmaf(p, t, 0.254829592f);
    p *= t;
    const float e  = __expf(-ax * ax);
    const float er = __builtin_fmaf(-p, e, 1.0f);     // erf(|x|) in [0,1)
    return 0.5f * v * (1.0f + copysignf(er, v));
}

// ================= 256x256 GEMM (B^T weights), BK=64, mfma 16x16x32 ===============
// 8 waves (2 row x 4 col), per-wave C = 128x64. LDS 128 KiB: A dbuf 2x32KB, B dbuf
// 2x32KB; rows of 128 B (8 chunks of 16 B), XOR chunk swizzle:
//   sA physical chunk p = logical ^ (row&7); sB p = logical ^ ((row>>2)&7).
// global_load_lds dst linear (base + tid*16); source chunk pre-permuted.
//
// ONE barrier per K-tile + within-wave counted-lgkm read-ahead (m218 mechanism):
//   issue bF0(4) | aF-mh0(8) | bF1(4)  [DS retires in order; SCB pins issue order]
//   lgkm(4)  -> bF0+aF ready, bF1 still flying -> MFMA(0,0) hides bF1 drain
//   lgkm(0)  -> MFMA(0,1); then aF-mh1 reuses aF regs (mh0 dead after (0,1))
//   lgkm(0)  -> MFMA(1,1); MFMA(1,0)
// Waves drift freely inside the tile (no mid-tile barriers): one wave's exposed
// A-mh1 drain hides under the other's MFMA clusters; setprio(1) arbitrates.
// Stage ledger: all 8 loads for tile t+1 -> OTH issued spread through tile t
// (legal: at tile-(t-1)-end barrier every wave's OTH reads were retired, since
// each wave's final lgkm(0) precedes it). Tile end: vmcnt(0) (issued >=2000cy
// earlier -> free drain) + barrier => staged t+1 visible to all waves.
#define SCB() __builtin_amdgcn_sched_barrier(0)
#define BAR() do { __builtin_amdgcn_s_barrier(); SCB(); } while (0)
#define LGKM(n) do { asm volatile("s_waitcnt lgkmcnt(" #n ")" ::: "memory"); SCB(); } while (0)
#define VMW(n) do { asm volatile("s_waitcnt vmcnt(" #n ")" ::: "memory"); SCB(); } while (0)

__device__ __forceinline__ void rdA(const char* base, bf16x8 (&aF)[4][2], int px0, int px1) {
#pragma unroll
    for (int ii = 0; ii < 4; ++ii) {
        aF[ii][0] = *(const bf16x8*)(base + ii * 2048 + px0);
        aF[ii][1] = *(const bf16x8*)(base + ii * 2048 + px1);
    }
}
__device__ __forceinline__ void rdB(const char* base, bf16x8 (&bF)[2][2], int px0, int px1) {
#pragma unroll
    for (int jj = 0; jj < 2; ++jj) {
        bF[jj][0] = *(const bf16x8*)(base + jj * 128 + px0);
        bF[jj][1] = *(const bf16x8*)(base + jj * 128 + px1);
    }
}
template <int MI, int NI>
__device__ __forceinline__ void mfmaQ(f32x4 (&acc)[8][4], const bf16x8 (&aF)[4][2],
                                      const bf16x8 (&bF)[2][2]) {
    __builtin_amdgcn_s_setprio(1);
#pragma unroll
    for (int ii = 0; ii < 4; ++ii)
#pragma unroll
        for (int jj = 0; jj < 2; ++jj) {
            acc[MI * 4 + ii][NI * 2 + jj] = __builtin_amdgcn_mfma_f32_16x16x32_bf16(
                aF[ii][0], bF[jj][0], acc[MI * 4 + ii][NI * 2 + jj], 0, 0, 0);
            acc[MI * 4 + ii][NI * 2 + jj] = __builtin_amdgcn_mfma_f32_16x16x32_bf16(
                aF[ii][1], bF[jj][1], acc[MI * 4 + ii][NI * 2 + jj], 0, 0, 0);
        }
    __builtin_amdgcn_s_setprio(0);
}

// KOFF in elements (= t*64). 131072 elems = 128 rows * K. S1 gates tile-(t+1)
// staging (all 8 halves -> OTH).
#define TILE(CUR, OTH, KOFF, S1) do { \
    const char* aB_ = aRd + (CUR) * 32768; \
    const char* bB_ = bRd + (CUR) * 32768; \
    if (S1) { load16(aS0 + (KOFF) + 64, dA + (OTH) * 32768); \
              load16(aS1 + (KOFF) + 64, dA + (OTH) * 32768 + 8192); } \
    rdB(bB_, bF0, px0, px1); SCB(); \
    rdA(aB_, aF, px0, px1); SCB(); \
    rdB(bB_ + 256, bF1, px0, px1); SCB(); \
    if (S1) { load16(aS0 + 131072 + (KOFF) + 64, dA + (OTH) * 32768 + 16384); \
              load16(aS1 + 131072 + (KOFF) + 64, dA + (OTH) * 32768 + 24576); } \
    LGKM(4); \
    mfmaQ<0, 0>(acc, aF, bF0); \
    if (S1) { load16(bS0 + (KOFF) + 64, dB + (OTH) * 32768); \
              load16(bS1 + (KOFF) + 64, dB + (OTH) * 32768 + 8192); } \
    LGKM(0); \
    mfmaQ<0, 1>(acc, aF, bF1); \
    rdA(aB_ + 8192, aF, px0, px1); SCB(); \
    if (S1) { load16(bS0 + 131072 + (KOFF) + 64, dB + (OTH) * 32768 + 16384); \
              load16(bS1 + 131072 + (KOFF) + 64, dB + (OTH) * 32768 + 24576); } \
    LGKM(0); \
    mfmaQ<1, 1>(acc, aF, bF1); \
    mfmaQ<1, 0>(acc, aF, bF0); \
} while (0)

template <int EPI>
__global__ __launch_bounds__(512, 2) void gemm256(
        const __hip_bfloat16* __restrict__ A,
        const __hip_bfloat16* __restrict__ B,
        const float* __restrict__ bias,
        const float* __restrict__ resid,
        __hip_bfloat16* __restrict__ outb,
        float* __restrict__ outf) {
    constexpr int K = 1024, N = 1024;
    __shared__ __align__(16) char lds[131072];
    char* sA = lds;            // 2 x 32KB A buffers
    char* sB = lds + 65536;    // 2 x 32KB B buffers

    const int tid  = threadIdx.x;
    const int lane = tid & 63;
    const int w    = tid >> 6;
    const int wr   = w >> 2;       // 0..1 wave row
    const int wc   = w & 3;        // 0..3 wave col
    const int f    = lane & 15;
    const int h    = lane >> 4;
    const int bm   = blockIdx.x * 256;
    const int bn   = blockIdx.y * 256;

    // staging sources: half of 128 rows x 8 chunks = 1024 chunk-ids; 512 thr x 2 loads
    const int cid0 = tid, cid1 = tid + 512;
    const __hip_bfloat16* aS0 = A + (size_t)(bm + (cid0 >> 3)) * K + (((cid0 & 7) ^ ((cid0 >> 3) & 7)) << 3);
    const __hip_bfloat16* aS1 = A + (size_t)(bm + (cid1 >> 3)) * K + (((cid1 & 7) ^ ((cid1 >> 3) & 7)) << 3);
    const __hip_bfloat16* bS0 = B + (size_t)(bn + (cid0 >> 3)) * K + (((cid0 & 7) ^ ((cid0 >> 5) & 7)) << 3);
    const __hip_bfloat16* bS1 = B + (size_t)(bn + (cid1 >> 3)) * K + (((cid1 & 7) ^ ((cid1 >> 5) & 7)) << 3);
    char* dA = sA + tid * 16;  // linear dst; per-wave uniform base + lane*16
    char* dB = sB + tid * 16;

    // fragment read bases (verified layout)
    const int pxk = (f & 7) * 16;
    const int px0 = (h * 16) ^ pxk;
    const int px1 = ((4 + h) * 16) ^ pxk;
    const char* aRd = sA + (size_t)(wr * 128 + f) * 128;    // + buf + mh*8192 + ii*2048 + px
    const char* bRd = sB + (size_t)(wc * 64 + 4 * f) * 128; // + buf + j*128 + px

    f32x4 acc[8][4] = {};
    bf16x8 aF[4][2], bF0[2][2], bF1[2][2];

    // prologue: tile0 (all 4 halves) -> buf0; drain; barrier.
    load16(bS0, dB);                  load16(bS1, dB + 8192);
    load16(bS0 + 131072, dB + 16384); load16(bS1 + 131072, dB + 24576);
    load16(aS0, dA);                  load16(aS1, dA + 8192);
    load16(aS0 + 131072, dA + 16384); load16(aS1 + 131072, dA + 24576);
    VMW(0);
    BAR();

#pragma unroll 1
    for (int it = 0; it < 7; ++it) {          // t = 0..13
        const int k0 = it << 7;
        TILE(0, 1, k0, true);
        VMW(0); BAR();
        TILE(1, 0, k0 + 64, true);
        VMW(0); BAR();
    }
    // t = 14: stage tile-15 -> buf1; drain; barrier
    TILE(0, 1, 896, true);
    VMW(0); BAR();
    // t = 15: no stages, no end sync
    TILE(1, 0, 960, false);

    // epilogue: lane owns rows bm+wr*128+i*16+h*4+r, cols bn+wc*64+4f..+3 (j contiguous)
    const int colb = bn + wc * 64 + f * 4;
    const float4 bias4 = *(const float4*)(bias + colb);
#pragma unroll
    for (int i = 0; i < 8; ++i) {
#pragma unroll
        for (int r = 0; r < 4; ++r) {
            const size_t grow = (size_t)(bm + wr * 128 + i * 16 + h * 4 + r);
            float v0 = acc[i][0][r] + bias4.x;
            float v1 = acc[i][1][r] + bias4.y;
            float v2 = acc[i][2][r] + bias4.z;
            float v3 = acc[i][3][r] + bias4.w;
            if (EPI == 0) {
                bh4 o;
                o.x = __float2bfloat16(gelu_exact(v0));
                o.y = __float2bfloat16(gelu_exact(v1));
                o.z = __float2bfloat16(gelu_exact(v2));
                o.w = __float2bfloat16(gelu_exact(v3));
                *(bh4*)(outb + grow * N + colb) = o;
            } else {
                const float4 rs = *(const float4*)(resid + grow * N + colb);
                float4 o = {v0 + rs.x, v1 + rs.y, v2 + rs.z, v3 + rs.w};
                *(float4*)(outf + grow * N + colb) = o;
            }
        }
    }
}

extern "C" void kernel_launch(void* const* d_in, const int* in_sizes, int n_in,
                              void* d_out, int out_size, void* d_ws, size_t ws_size,
                              hipStream_t stream) {
    const float* x     = (const float*)d_in[0];
    const float* gamma = (const float*)d_in[1];
    const float* beta  = (const float*)d_in[2];
    const float* w1    = (const float*)d_in[3];
    const float* b1    = (const float*)d_in[4];
    const float* w2    = (const float*)d_in[5];
    const float* b2    = (const float*)d_in[6];
    float* out = (float*)d_out;

    const int M = in_sizes[0] / 1024;   // 16384

    char* ws = (char*)d_ws;
    __hip_bfloat16* hn  = (__hip_bfloat16*)ws;                          // 32 MiB
    __hip_bfloat16* h1  = (__hip_bfloat16*)(ws + (size_t)M * 2048);     // 32 MiB
    __hip_bfloat16* w1b = (__hip_bfloat16*)(ws + (size_t)M * 4096);     // 2 MiB
    __hip_bfloat16* w2b = (__hip_bfloat16*)(ws + (size_t)M * 4096 + 2097152);

    const int nln = M / 4;   // 4096 LN blocks + 1024 cvt blocks
    pre_kernel<<<nln + 1024, 256, 0, stream>>>(x, gamma, beta, w1, w2, hn, w1b, w2b, nln);
    // grid x = bm index: linear id % 8 = bm % 8 -> the 4 bn-blocks of one bm strip
    // land on one XCD (A-strip L2 reuse); 256 blocks = exactly 1/CU.
    gemm256<0><<<dim3(M / 256, 4), 512, 0, stream>>>(hn, w1b, b1, nullptr, h1, nullptr);
    gemm256<1><<<dim3(M / 256, 4), 512, 0, stream>>>(h1, w2b, b2, x, nullptr, out);
}